// Round 1
// baseline (192.358 us; speedup 1.0000x reference)
//
#include <hip/hip_runtime.h>
#include <math.h>

// RMAC for x[64][512][32][32] fp32, L=3, OVR=0.4, EPS=1e-6.
// Static region set for H=W=32:
//   l=1: (0,0,32)                          -> counted TWICE (global pool + region)
//   l=2: (i,j,21) for i,j in {0,11}
//   l=3: (i,j,16) for i,j in {0,8,16}
// 14 distinct pooled vectors vt[r][b][c]; out[b][c] = sum_r w_r * vt / (||vt||_c + eps)

#define B_ 64
#define C_ 512
#define BC 32768            // B_*C_
#define TPB 8               // tiles (b,c pairs) per block in pool kernel
#define LDS_STRIDE 33       // 32 + 1 pad -> conflict-free column reads

__global__ __launch_bounds__(256) void rmac_pool_kernel(const float* __restrict__ x,
                                                        float* __restrict__ vt) {
    // lds[tile][h*33 + w] : 8 * 1056 floats = 33 KB
    __shared__ float lds[TPB][32 * LDS_STRIDE];
    // per-column row-range maxes: 6 ranges, padded row
    __shared__ float rmax[TPB][6][LDS_STRIDE];

    const int t = threadIdx.x;
    const long long base = (long long)blockIdx.x * (TPB * 1024);
    const float4* xv = (const float4*)(x + base);

    // ---- load 8 tiles (2048 float4) coalesced, scatter into padded LDS ----
#pragma unroll
    for (int it = 0; it < 8; ++it) {
        int i = it * 256 + t;          // float4 index within block's 8 tiles
        float4 v = xv[i];
        int tile = i >> 8;             // 256 float4 per tile
        int rem  = i & 255;
        int h    = rem >> 3;           // 8 float4 per 32-wide row
        int ws   = rem & 7;
        float* dst = &lds[tile][h * LDS_STRIDE + ws * 4];
        dst[0] = v.x; dst[1] = v.y; dst[2] = v.z; dst[3] = v.w;
    }
    __syncthreads();

    // ---- per-column row-range maxes (thread = (tile, w)) ----
    {
        int tile = t >> 5;
        int w    = t & 31;
        const float* col = &lds[tile][w];
        float m0 = -INFINITY, m1 = -INFINITY, m2 = -INFINITY;
        float m3 = -INFINITY, m4 = -INFINITY, m5 = -INFINITY;
#pragma unroll
        for (int h = 0; h < 32; ++h) {
            float v = col[h * LDS_STRIDE];
            m0 = fmaxf(m0, v);                       // rows [0,32)
            if (h < 21)            m1 = fmaxf(m1, v); // rows [0,21)
            if (h >= 11)           m2 = fmaxf(m2, v); // rows [11,32)
            if (h < 16)            m3 = fmaxf(m3, v); // rows [0,16)
            if (h >= 8 && h < 24)  m4 = fmaxf(m4, v); // rows [8,24)
            if (h >= 16)           m5 = fmaxf(m5, v); // rows [16,32)
        }
        rmax[tile][0][w] = m0; rmax[tile][1][w] = m1; rmax[tile][2][w] = m2;
        rmax[tile][3][w] = m3; rmax[tile][4][w] = m4; rmax[tile][5][w] = m5;
    }
    __syncthreads();

    // ---- 14 region reductions over column ranges (8 tiles * 14 = 112 threads) ----
    if (t < TPB * 14) {
        const int tl = t / 14;
        const int r  = t % 14;
        // region -> (row-range idx, col_lo, col_hi)
        const int rr_[14]  = {0, 1, 1, 2, 2, 3, 3, 3, 4, 4, 4, 5, 5, 5};
        const int clo[14]  = {0, 0, 11, 0, 11, 0, 8, 16, 0, 8, 16, 0, 8, 16};
        const int chi[14]  = {32, 21, 32, 21, 32, 16, 24, 32, 16, 24, 32, 16, 24, 32};
        const float* src = rmax[tl][rr_[r]];
        float m = -INFINITY;
        for (int c = clo[r]; c < chi[r]; ++c) m = fmaxf(m, src[c]);
        const int tidx = blockIdx.x * TPB + tl;   // = b*C_ + c
        vt[r * BC + tidx] = m;
    }
}

__global__ __launch_bounds__(512) void rmac_norm_kernel(const float* __restrict__ vt,
                                                        float* __restrict__ out) {
    const int b = blockIdx.x;
    const int c = threadIdx.x;

    float v[14];
#pragma unroll
    for (int r = 0; r < 14; ++r) v[r] = vt[r * BC + b * C_ + c];

    __shared__ float partial[14][8];
    __shared__ float inv[14];
    const int wid  = c >> 6;
    const int lane = c & 63;

#pragma unroll
    for (int r = 0; r < 14; ++r) {
        float s = v[r] * v[r];
#pragma unroll
        for (int off = 32; off > 0; off >>= 1)
            s += __shfl_down(s, off, 64);
        if (lane == 0) partial[r][wid] = s;
    }
    __syncthreads();

    if (c < 14) {
        float s = 0.f;
#pragma unroll
        for (int wI = 0; wI < 8; ++wI) s += partial[c][wI];
        inv[c] = 1.0f / (sqrtf(s) + 1e-6f);
    }
    __syncthreads();

    float acc = 2.0f * v[0] * inv[0];   // global pool counted twice (l=1 region == global)
#pragma unroll
    for (int r = 1; r < 14; ++r) acc += v[r] * inv[r];
    out[b * C_ + c] = acc;
}

extern "C" void kernel_launch(void* const* d_in, const int* in_sizes, int n_in,
                              void* d_out, int out_size, void* d_ws, size_t ws_size,
                              hipStream_t stream) {
    const float* x  = (const float*)d_in[0];
    float* out      = (float*)d_out;
    float* vt       = (float*)d_ws;   // 14 * 32768 floats = 1.75 MB

    rmac_pool_kernel<<<BC / TPB, 256, 0, stream>>>(x, vt);   // 4096 blocks
    rmac_norm_kernel<<<B_, 512, 0, stream>>>(vt, out);       // 64 blocks
}